// Round 1
// baseline (296.310 us; speedup 1.0000x reference)
//
#include <hip/hip_runtime.h>

// LSTMClassifier: B=4096, T=128, I=32, H=64, 2-layer LSTM + MLP head.
// Fused persistent-block design: 256 blocks x 256 threads (4 waves), each block
// owns 16 batch rows for all 128 timesteps of BOTH layers. Weights live in
// per-wave MFMA B-fragments (registers) for the whole kernel. f16 MFMA inputs,
// fp32 accumulate/state.

#define TT 128
#define II 32
#define HH 64

typedef _Float16 half8 __attribute__((ext_vector_type(8)));
typedef float floatx4 __attribute__((ext_vector_type(4)));

__device__ __forceinline__ float fsig(float x) {
    return __builtin_amdgcn_rcpf(1.0f + __expf(-x));
}
__device__ __forceinline__ float ftanhf(float x) {
    // tanh(x) = 1 - 2/(1+exp(2x)); saturates correctly for |x| large
    return 1.0f - 2.0f * __builtin_amdgcn_rcpf(1.0f + __expf(2.0f * x));
}

// Load 8 consecutive fp32 of row n (K-major) and convert to an f16 MFMA fragment.
__device__ __forceinline__ half8 load_w_frag(const float* __restrict__ W, int n, int K, int k0) {
    const float* p = W + (size_t)n * K + k0;
    float4 a = *(const float4*)p;
    float4 b = *(const float4*)(p + 4);
    half8 h;
    h[0] = (_Float16)a.x; h[1] = (_Float16)a.y; h[2] = (_Float16)a.z; h[3] = (_Float16)a.w;
    h[4] = (_Float16)b.x; h[5] = (_Float16)b.y; h[6] = (_Float16)b.z; h[7] = (_Float16)b.w;
    return h;
}

__global__ __launch_bounds__(256, 1) void lstm_fused(
    const float* __restrict__ x,
    const float* __restrict__ Wih0, const float* __restrict__ Whh0,
    const float* __restrict__ bih0, const float* __restrict__ bhh0,
    const float* __restrict__ Wih1, const float* __restrict__ Whh1,
    const float* __restrict__ bih1, const float* __restrict__ bhh1,
    const float* __restrict__ Wc1, const float* __restrict__ bc1,
    const float* __restrict__ Wc2, const float* __restrict__ bc2,
    float* __restrict__ out)
{
    // +8 f16 padding => 2-way LDS bank aliasing on b128 reads (free per m136)
    __shared__ __align__(16) _Float16 xs[16][40];
    __shared__ __align__(16) _Float16 h0s[16][72];
    __shared__ __align__(16) _Float16 h1s[16][72];
    __shared__ __align__(16) float h1f[16][68];   // final-step h1 in fp32 for classifier
    __shared__ float hid[16][32];

    const int tid = threadIdx.x;
    const int w = tid >> 6;       // wave 0..3
    const int lane = tid & 63;
    const int q = lane >> 4;      // quad 0..3
    const int lr = lane & 15;
    const int b0 = blockIdx.x * 16;

    // ---- persistent weight fragments (registers, whole kernel) ----
    // Wave w owns gate-column tiles n_base = (w + 4g)*16, g = gate (i,f,g,o),
    // so all four gates for channels j in [16w,16w+16) live in this wave.
    // B-frag layout: lane holds B[k][n] with n = tile + (lane&15), k = 8*quad + j.
    // B = W^T  =>  lane reads W[n][8q .. 8q+8) (contiguous).
    half8 bx0[4], bh0[4][2], bi1[4][2], bh1[4][2];
    float bias0v[4], bias1v[4];
    #pragma unroll
    for (int g = 0; g < 4; ++g) {
        int n = (w + 4 * g) * 16 + lr;
        bx0[g]    = load_w_frag(Wih0, n, 32, q * 8);
        bh0[g][0] = load_w_frag(Whh0, n, 64, q * 8);
        bh0[g][1] = load_w_frag(Whh0, n, 64, 32 + q * 8);
        bi1[g][0] = load_w_frag(Wih1, n, 64, q * 8);
        bi1[g][1] = load_w_frag(Wih1, n, 64, 32 + q * 8);
        bh1[g][0] = load_w_frag(Whh1, n, 64, q * 8);
        bh1[g][1] = load_w_frag(Whh1, n, 64, 32 + q * 8);
        bias0v[g] = bih0[n] + bhh0[n];   // xproj folds (bih+bhh) once
        bias1v[g] = bih1[n] + bhh1[n];
    }

    // zero-init h state in LDS
    for (int i = tid; i < 16 * 72; i += 256) {
        ((_Float16*)h0s)[i] = (_Float16)0.0f;
        ((_Float16*)h1s)[i] = (_Float16)0.0f;
    }

    float c0r[4] = {0.f, 0.f, 0.f, 0.f};
    float c1r[4] = {0.f, 0.f, 0.f, 0.f};

    // x staging map: thread -> (row m, 2 consecutive floats) ; coalesced 128B/row
    const int xm = tid >> 4;
    const int xf = (tid & 15) * 2;
    const float* xrow = x + ((size_t)(b0 + xm) * TT) * II + xf;

    for (int t = 0; t < TT; ++t) {
        // stage x_t -> LDS f16
        float2 xv = *(const float2*)(xrow + (size_t)t * II);
        xs[xm][xf]     = (_Float16)xv.x;
        xs[xm][xf + 1] = (_Float16)xv.y;
        __syncthreads();  // b0: xs(t) + h1s(t-1) visible; h0s(t-1) stable

        // ---- layer 0: gates = bias0 + x_t Wih0^T + h0 Whh0^T ----
        // A-frag: lane holds A[m = lane&15][k = 8*quad + j]
        half8 xfrag = *(const half8*)&xs[lr][q * 8];
        half8 h0a   = *(const half8*)&h0s[lr][q * 8];
        half8 h0b   = *(const half8*)&h0s[lr][32 + q * 8];
        floatx4 a0[4];
        #pragma unroll
        for (int g = 0; g < 4; ++g) {
            floatx4 acc = {bias0v[g], bias0v[g], bias0v[g], bias0v[g]};
            acc = __builtin_amdgcn_mfma_f32_16x16x32_f16(xfrag, bx0[g],    acc, 0, 0, 0);
            acc = __builtin_amdgcn_mfma_f32_16x16x32_f16(h0a,   bh0[g][0], acc, 0, 0, 0);
            acc = __builtin_amdgcn_mfma_f32_16x16x32_f16(h0b,   bh0[g][1], acc, 0, 0, 0);
            a0[g] = acc;
        }
        // eltwise: lane owns (m = 4q+r, j = 16w + lr), r=0..3 ; c stays fp32 in regs
        float h0new[4];
        #pragma unroll
        for (int r = 0; r < 4; ++r) {
            float ig = fsig(a0[0][r]);
            float fg = fsig(a0[1][r]);
            float gg = ftanhf(a0[2][r]);
            float og = fsig(a0[3][r]);
            float c = fg * c0r[r] + ig * gg;
            c0r[r] = c;
            h0new[r] = og * ftanhf(c);
        }
        __syncthreads();  // b1: all waves done reading h0s(t-1)
        #pragma unroll
        for (int r = 0; r < 4; ++r)
            h0s[q * 4 + r][w * 16 + lr] = (_Float16)h0new[r];
        __syncthreads();  // b2: h0s(t) visible

        // ---- layer 1: gates = bias1 + h0(t) Wih1^T + h1 Whh1^T ----
        half8 g0a = *(const half8*)&h0s[lr][q * 8];
        half8 g0b = *(const half8*)&h0s[lr][32 + q * 8];
        half8 h1a = *(const half8*)&h1s[lr][q * 8];
        half8 h1b = *(const half8*)&h1s[lr][32 + q * 8];
        floatx4 a1[4];
        #pragma unroll
        for (int g = 0; g < 4; ++g) {
            floatx4 acc = {bias1v[g], bias1v[g], bias1v[g], bias1v[g]};
            acc = __builtin_amdgcn_mfma_f32_16x16x32_f16(g0a, bi1[g][0], acc, 0, 0, 0);
            acc = __builtin_amdgcn_mfma_f32_16x16x32_f16(g0b, bi1[g][1], acc, 0, 0, 0);
            acc = __builtin_amdgcn_mfma_f32_16x16x32_f16(h1a, bh1[g][0], acc, 0, 0, 0);
            acc = __builtin_amdgcn_mfma_f32_16x16x32_f16(h1b, bh1[g][1], acc, 0, 0, 0);
            a1[g] = acc;
        }
        float h1new[4];
        #pragma unroll
        for (int r = 0; r < 4; ++r) {
            float ig = fsig(a1[0][r]);
            float fg = fsig(a1[1][r]);
            float gg = ftanhf(a1[2][r]);
            float og = fsig(a1[3][r]);
            float c = fg * c1r[r] + ig * gg;
            c1r[r] = c;
            h1new[r] = og * ftanhf(c);
        }
        __syncthreads();  // b3: all waves done reading h1s(t-1)
        #pragma unroll
        for (int r = 0; r < 4; ++r) {
            h1s[q * 4 + r][w * 16 + lr] = (_Float16)h1new[r];
            if (t == TT - 1) h1f[q * 4 + r][w * 16 + lr] = h1new[r];
        }
        // next iteration's b0 publishes h1s(t) before GEMM1 reads it
    }
    __syncthreads();

    // ---- classifier (fp32): hidden = relu(hT Wc1^T + bc1); out = hidden Wc2^T + bc2
    {
        int m = tid >> 4;
        int u = (tid & 15) * 2;
        float a = bc1[u], b = bc1[u + 1];
        const float* w0 = Wc1 + u * 64;
        const float* w1 = Wc1 + (u + 1) * 64;
        #pragma unroll 8
        for (int k = 0; k < 64; ++k) {
            float hv = h1f[m][k];
            a += hv * w0[k];
            b += hv * w1[k];
        }
        hid[m][u]     = fmaxf(a, 0.f);
        hid[m][u + 1] = fmaxf(b, 0.f);
    }
    __syncthreads();
    if (tid < 16) {
        float o = bc2[0];
        #pragma unroll
        for (int u = 0; u < 32; ++u) o += hid[tid][u] * Wc2[u];
        out[b0 + tid] = o;
    }
}

extern "C" void kernel_launch(void* const* d_in, const int* in_sizes, int n_in,
                              void* d_out, int out_size, void* d_ws, size_t ws_size,
                              hipStream_t stream) {
    (void)in_sizes; (void)n_in; (void)d_ws; (void)ws_size; (void)out_size;
    const float* x    = (const float*)d_in[0];
    const float* Wih0 = (const float*)d_in[1];
    const float* Whh0 = (const float*)d_in[2];
    const float* bih0 = (const float*)d_in[3];
    const float* bhh0 = (const float*)d_in[4];
    const float* Wih1 = (const float*)d_in[5];
    const float* Whh1 = (const float*)d_in[6];
    const float* bih1 = (const float*)d_in[7];
    const float* bhh1 = (const float*)d_in[8];
    const float* Wc1  = (const float*)d_in[9];
    const float* bc1  = (const float*)d_in[10];
    const float* Wc2  = (const float*)d_in[11];
    const float* bc2  = (const float*)d_in[12];
    lstm_fused<<<dim3(256), dim3(256), 0, stream>>>(
        x, Wih0, Whh0, bih0, bhh0, Wih1, Whh1, bih1, bhh1, Wc1, bc1, Wc2, bc2,
        (float*)d_out);
}

// Round 2
// 226.504 us; speedup vs baseline: 1.3082x; 1.3082x over previous
//
#include <hip/hip_runtime.h>

// LSTMClassifier: B=4096, T=128, I=32, H=64, 2-layer LSTM + MLP head.
// Round 2: layer-pipelined persistent blocks. 256 blocks x 512 threads (8 waves).
// Waves 0-3 compute layer 0 at step t; waves 4-7 compute layer 1 at step t-1
// (one-step skew) in the SAME compute phase -> 2 barriers/step instead of 4,
// 2 waves/SIMD TLP instead of 1. Weights persist in per-wave MFMA B-fragments.
// f16 MFMA operands, fp32 accumulate/state.

#define TT 128
#define II 32
#define HH 64

typedef _Float16 half8 __attribute__((ext_vector_type(8)));
typedef float floatx4 __attribute__((ext_vector_type(4)));

__device__ __forceinline__ float fsig(float x) {
    return __builtin_amdgcn_rcpf(1.0f + __expf(-x));
}
__device__ __forceinline__ float ftanhf(float x) {
    // tanh(x) = 1 - 2/(1+exp(2x)); saturates correctly for |x| large
    return 1.0f - 2.0f * __builtin_amdgcn_rcpf(1.0f + __expf(2.0f * x));
}

// Load 8 consecutive fp32 of row n (K-major) and convert to an f16 MFMA fragment.
__device__ __forceinline__ half8 load_w_frag(const float* __restrict__ W, int n, int K, int k0) {
    const float* p = W + (size_t)n * K + k0;
    float4 a = *(const float4*)p;
    float4 b = *(const float4*)(p + 4);
    half8 h;
    h[0] = (_Float16)a.x; h[1] = (_Float16)a.y; h[2] = (_Float16)a.z; h[3] = (_Float16)a.w;
    h[4] = (_Float16)b.x; h[5] = (_Float16)b.y; h[6] = (_Float16)b.z; h[7] = (_Float16)b.w;
    return h;
}

__global__ __launch_bounds__(512, 2) void lstm_fused(
    const float* __restrict__ x,
    const float* __restrict__ Wih0, const float* __restrict__ Whh0,
    const float* __restrict__ bih0, const float* __restrict__ bhh0,
    const float* __restrict__ Wih1, const float* __restrict__ Whh1,
    const float* __restrict__ bih1, const float* __restrict__ bhh1,
    const float* __restrict__ Wc1, const float* __restrict__ bc1,
    const float* __restrict__ Wc2, const float* __restrict__ bc2,
    float* __restrict__ out)
{
    // +8 f16 padding keeps 16B alignment (stride 144B) with only 2-way
    // bank aliasing on b128 reads (free per m136).
    __shared__ __align__(16) _Float16 xs[16][40];
    __shared__ __align__(16) _Float16 h0s[16][72];
    __shared__ __align__(16) _Float16 h1s[16][72];
    __shared__ __align__(16) float h1f[16][68];   // final-step h1 in fp32 for classifier
    __shared__ float hid[16][32];

    const int tid  = threadIdx.x;
    const int wid  = tid >> 6;        // wave 0..7
    const int w4   = wid & 3;         // gate-column group within the layer
    const bool isL0 = (wid < 4);
    const int lane = tid & 63;
    const int q  = lane >> 4;         // quad 0..3
    const int lr = lane & 15;
    const int b0 = blockIdx.x * 16;

    // ---- persistent weight fragments (registers, whole kernel) ----
    // Within a layer, wave group w4 owns gate-column tiles n = (w4 + 4g)*16,
    // g = gate (i,f,g,o): all four gates for channels j in [16*w4, 16*w4+16)
    // live in the same wave -> eltwise is lane-local.
    // B-frag: lane holds B[k][n], n = tile + lr, k = 8q + j; B = W^T so the
    // lane reads W[n][8q..8q+8) contiguously.
    half8 bx0[4], bh0[4][2];          // layer-0 waves
    half8 bi1[4][2], bh1[4][2];       // layer-1 waves
    float biasv[4];
    if (isL0) {
        #pragma unroll
        for (int g = 0; g < 4; ++g) {
            int n = (w4 + 4 * g) * 16 + lr;
            bx0[g]    = load_w_frag(Wih0, n, 32, q * 8);
            bh0[g][0] = load_w_frag(Whh0, n, 64, q * 8);
            bh0[g][1] = load_w_frag(Whh0, n, 64, 32 + q * 8);
            biasv[g]  = bih0[n] + bhh0[n];
        }
    } else {
        #pragma unroll
        for (int g = 0; g < 4; ++g) {
            int n = (w4 + 4 * g) * 16 + lr;
            bi1[g][0] = load_w_frag(Wih1, n, 64, q * 8);
            bi1[g][1] = load_w_frag(Wih1, n, 64, 32 + q * 8);
            bh1[g][0] = load_w_frag(Whh1, n, 64, q * 8);
            bh1[g][1] = load_w_frag(Whh1, n, 64, 32 + q * 8);
            biasv[g]  = bih1[n] + bhh1[n];
        }
    }

    // zero-init h state in LDS (h0(-1) = h1(-1) = 0)
    for (int i = tid; i < 16 * 72; i += 512) {
        ((_Float16*)h0s)[i] = (_Float16)0.0f;
        ((_Float16*)h1s)[i] = (_Float16)0.0f;
    }

    float cr[4] = {0.f, 0.f, 0.f, 0.f};   // c state for this wave's layer

    // x staging (layer-0 waves only): thread -> (row xm, 2 consecutive floats)
    const int xm = (tid >> 4) & 15;
    const int xf = (tid & 15) * 2;
    const float* xrow = x + ((size_t)(b0 + xm) * TT) * II + xf;
    float2 xbuf = {0.f, 0.f};
    if (isL0) {
        float2 x0 = *(const float2*)(xrow);            // x(0)
        xs[xm][xf]     = (_Float16)x0.x;
        xs[xm][xf + 1] = (_Float16)x0.y;
        if (TT > 1) xbuf = *(const float2*)(xrow + 1 * II);  // x(1)
    }

    // Pipeline: iteration k computes h0(k) on waves 0-3 (k < TT) and h1(k-1)
    // on waves 4-7 (k >= 1). Single-buffered LDS is WAR-safe: all reads of
    // h*(k-1)/xs(k) finish before barrier B; writes of h*(k)/xs(k+1) follow it.
    for (int k = 0; k <= TT; ++k) {
        __syncthreads();  // barrier A: writes from iteration k-1 visible

        const bool doL0 = isL0 && (k < TT);
        const bool doL1 = (!isL0) && (k >= 1);
        float hnew[4];
        float2 xnew = xbuf;

        if (doL0) {
            // gates = bias0 + x(k) Wih0^T + h0(k-1) Whh0^T
            half8 xfrag = *(const half8*)&xs[lr][q * 8];
            half8 h0a   = *(const half8*)&h0s[lr][q * 8];
            half8 h0b   = *(const half8*)&h0s[lr][32 + q * 8];
            if (k + 2 < TT) xnew = *(const float2*)(xrow + (size_t)(k + 2) * II);
            floatx4 a0[4];
            #pragma unroll
            for (int g = 0; g < 4; ++g) {
                floatx4 accA = {biasv[g], biasv[g], biasv[g], biasv[g]};
                floatx4 z = {0.f, 0.f, 0.f, 0.f};
                accA = __builtin_amdgcn_mfma_f32_16x16x32_f16(xfrag, bx0[g],    accA, 0, 0, 0);
                accA = __builtin_amdgcn_mfma_f32_16x16x32_f16(h0a,   bh0[g][0], accA, 0, 0, 0);
                floatx4 accB = __builtin_amdgcn_mfma_f32_16x16x32_f16(h0b, bh0[g][1], z, 0, 0, 0);
                a0[g] = accA + accB;
            }
            #pragma unroll
            for (int r = 0; r < 4; ++r) {
                float ig = fsig(a0[0][r]);
                float fg = fsig(a0[1][r]);
                float gg = ftanhf(a0[2][r]);
                float og = fsig(a0[3][r]);
                float c = fg * cr[r] + ig * gg;
                cr[r] = c;
                hnew[r] = og * ftanhf(c);
            }
        }
        if (doL1) {
            // gates = bias1 + h0(k-1) Wih1^T + h1(k-2) Whh1^T
            half8 g0a = *(const half8*)&h0s[lr][q * 8];
            half8 g0b = *(const half8*)&h0s[lr][32 + q * 8];
            half8 h1a = *(const half8*)&h1s[lr][q * 8];
            half8 h1b = *(const half8*)&h1s[lr][32 + q * 8];
            floatx4 a1[4];
            #pragma unroll
            for (int g = 0; g < 4; ++g) {
                floatx4 accA = {biasv[g], biasv[g], biasv[g], biasv[g]};
                floatx4 z = {0.f, 0.f, 0.f, 0.f};
                accA = __builtin_amdgcn_mfma_f32_16x16x32_f16(g0a, bi1[g][0], accA, 0, 0, 0);
                accA = __builtin_amdgcn_mfma_f32_16x16x32_f16(g0b, bi1[g][1], accA, 0, 0, 0);
                floatx4 accB = __builtin_amdgcn_mfma_f32_16x16x32_f16(h1a, bh1[g][0], z,    0, 0, 0);
                accB         = __builtin_amdgcn_mfma_f32_16x16x32_f16(h1b, bh1[g][1], accB, 0, 0, 0);
                a1[g] = accA + accB;
            }
            #pragma unroll
            for (int r = 0; r < 4; ++r) {
                float ig = fsig(a1[0][r]);
                float fg = fsig(a1[1][r]);
                float gg = ftanhf(a1[2][r]);
                float og = fsig(a1[3][r]);
                float c = fg * cr[r] + ig * gg;
                cr[r] = c;
                hnew[r] = og * ftanhf(c);
            }
        }

        __syncthreads();  // barrier B: all reads of step-(k-1) state done

        if (doL0) {
            #pragma unroll
            for (int r = 0; r < 4; ++r)
                h0s[q * 4 + r][w4 * 16 + lr] = (_Float16)hnew[r];
            if (k + 1 < TT) {
                xs[xm][xf]     = (_Float16)xbuf.x;
                xs[xm][xf + 1] = (_Float16)xbuf.y;
            }
            xbuf = xnew;
        }
        if (doL1) {
            if (k == TT) {
                #pragma unroll
                for (int r = 0; r < 4; ++r)
                    h1f[q * 4 + r][w4 * 16 + lr] = hnew[r];
            } else {
                #pragma unroll
                for (int r = 0; r < 4; ++r)
                    h1s[q * 4 + r][w4 * 16 + lr] = (_Float16)hnew[r];
            }
        }
    }
    __syncthreads();

    // ---- classifier (fp32): hidden = relu(hT Wc1^T + bc1); out = hidden Wc2^T + bc2
    if (tid < 256) {
        int m = tid >> 4;
        int u = (tid & 15) * 2;
        float a = bc1[u], b = bc1[u + 1];
        const float* w0 = Wc1 + u * 64;
        const float* w1 = Wc1 + (u + 1) * 64;
        #pragma unroll 8
        for (int kk = 0; kk < 64; ++kk) {
            float hv = h1f[m][kk];
            a += hv * w0[kk];
            b += hv * w1[kk];
        }
        hid[m][u]     = fmaxf(a, 0.f);
        hid[m][u + 1] = fmaxf(b, 0.f);
    }
    __syncthreads();
    if (tid < 16) {
        float o = bc2[0];
        #pragma unroll
        for (int u = 0; u < 32; ++u) o += hid[tid][u] * Wc2[u];
        out[b0 + tid] = o;
    }
}

extern "C" void kernel_launch(void* const* d_in, const int* in_sizes, int n_in,
                              void* d_out, int out_size, void* d_ws, size_t ws_size,
                              hipStream_t stream) {
    (void)in_sizes; (void)n_in; (void)d_ws; (void)ws_size; (void)out_size;
    const float* x    = (const float*)d_in[0];
    const float* Wih0 = (const float*)d_in[1];
    const float* Whh0 = (const float*)d_in[2];
    const float* bih0 = (const float*)d_in[3];
    const float* bhh0 = (const float*)d_in[4];
    const float* Wih1 = (const float*)d_in[5];
    const float* Whh1 = (const float*)d_in[6];
    const float* bih1 = (const float*)d_in[7];
    const float* bhh1 = (const float*)d_in[8];
    const float* Wc1  = (const float*)d_in[9];
    const float* bc1  = (const float*)d_in[10];
    const float* Wc2  = (const float*)d_in[11];
    const float* bc2  = (const float*)d_in[12];
    lstm_fused<<<dim3(256), dim3(512), 0, stream>>>(
        x, Wih0, Whh0, bih0, bhh0, Wih1, Whh1, bih1, bhh1, Wc1, bc1, Wc2, bc2,
        (float*)d_out);
}

// Round 3
// 205.987 us; speedup vs baseline: 1.4385x; 1.0996x over previous
//
#include <hip/hip_runtime.h>

// LSTMClassifier: B=4096, T=128, I=32, H=64, 2-layer LSTM + MLP head.
// Round 3: layer-pipelined persistent blocks, double-buffered LDS state ->
// ONE barrier per timestep. 256 blocks x 512 threads (8 waves): waves 0-3
// layer 0 at step k, waves 4-7 layer 1 at step k-1. Weights persist in
// per-wave MFMA B-fragments. f16 MFMA operands, fp32 accumulate/state.
// Eltwise uses fused sigma*tanh products: 8 transcendentals/cell (was 10).

#define TT 128
#define II 32
#define HH 64

typedef _Float16 half8 __attribute__((ext_vector_type(8)));
typedef float floatx4 __attribute__((ext_vector_type(4)));

#define LOG2E 1.4426950408889634f

// Load 8 consecutive fp32 of row n (K-major) and convert to an f16 MFMA fragment.
__device__ __forceinline__ half8 load_w_frag(const float* __restrict__ W, int n, int K, int k0) {
    const float* p = W + (size_t)n * K + k0;
    float4 a = *(const float4*)p;
    float4 b = *(const float4*)(p + 4);
    half8 h;
    h[0] = (_Float16)a.x; h[1] = (_Float16)a.y; h[2] = (_Float16)a.z; h[3] = (_Float16)a.w;
    h[4] = (_Float16)b.x; h[5] = (_Float16)b.y; h[6] = (_Float16)b.z; h[7] = (_Float16)b.w;
    return h;
}

// h = sigma(o)*tanh(c) style fused product: sigma(a)*tanh(b)
//   = (e^{2b}-1) / ((1+e^{-a})(e^{2b}+1));  b pre-clamped to +-15.
__device__ __forceinline__ float sig_tanh(float a, float b) {
    float bb = fminf(fmaxf(b, -15.f), 15.f);
    float u  = __builtin_amdgcn_exp2f(bb * (2.0f * LOG2E));
    float v  = __builtin_amdgcn_exp2f(-a * LOG2E);
    float num = u - 1.0f;
    float d1  = u + 1.0f;
    float den = fmaf(v, d1, d1);          // (1+v)*(u+1)
    return num * __builtin_amdgcn_rcpf(den);
}

__device__ __forceinline__ float fsig(float x) {
    return __builtin_amdgcn_rcpf(1.0f + __builtin_amdgcn_exp2f(-x * LOG2E));
}

__global__ __launch_bounds__(512, 2) void lstm_fused(
    const float* __restrict__ x,
    const float* __restrict__ Wih0, const float* __restrict__ Whh0,
    const float* __restrict__ bih0, const float* __restrict__ bhh0,
    const float* __restrict__ Wih1, const float* __restrict__ Whh1,
    const float* __restrict__ bih1, const float* __restrict__ bhh1,
    const float* __restrict__ Wc1, const float* __restrict__ bc1,
    const float* __restrict__ Wc2, const float* __restrict__ bc2,
    float* __restrict__ out)
{
    // Double-buffered state; +8 f16 padding keeps 16B alignment (stride 144B)
    // with only 2-way bank aliasing on b128 reads (free per m136).
    __shared__ __align__(16) _Float16 xs[2][16][40];
    __shared__ __align__(16) _Float16 h0s[2][16][72];
    __shared__ __align__(16) _Float16 h1s[2][16][72];
    __shared__ __align__(16) float h1f[16][68];   // final-step h1 (fp32) for classifier
    __shared__ float hid[16][32];

    const int tid  = threadIdx.x;
    const int wid  = tid >> 6;        // wave 0..7
    const int w4   = wid & 3;         // gate-column group within the layer
    const bool isL0 = (wid < 4);
    const int lane = tid & 63;
    const int q  = lane >> 4;         // quad 0..3
    const int lr = lane & 15;
    const int b0 = blockIdx.x * 16;

    // ---- persistent weight fragments (registers, whole kernel) ----
    // Wave group w4 owns gate-column tiles n = (w4 + 4g)*16, g in {i,f,g,o}:
    // all four gates for channels [16*w4, 16*w4+16) are lane-local at eltwise.
    // B-frag: lane holds B[k][n], n = tile + lr, k = 8q + j; B = W^T so the
    // lane reads W[n][8q..8q+8) contiguously.
    half8 bx0[4], bh0[4][2];          // layer-0 waves
    half8 bi1[4][2], bh1[4][2];       // layer-1 waves
    float biasv[4];
    if (isL0) {
        #pragma unroll
        for (int g = 0; g < 4; ++g) {
            int n = (w4 + 4 * g) * 16 + lr;
            bx0[g]    = load_w_frag(Wih0, n, 32, q * 8);
            bh0[g][0] = load_w_frag(Whh0, n, 64, q * 8);
            bh0[g][1] = load_w_frag(Whh0, n, 64, 32 + q * 8);
            biasv[g]  = bih0[n] + bhh0[n];
        }
    } else {
        #pragma unroll
        for (int g = 0; g < 4; ++g) {
            int n = (w4 + 4 * g) * 16 + lr;
            bi1[g][0] = load_w_frag(Wih1, n, 64, q * 8);
            bi1[g][1] = load_w_frag(Wih1, n, 64, 32 + q * 8);
            bh1[g][0] = load_w_frag(Whh1, n, 64, q * 8);
            bh1[g][1] = load_w_frag(Whh1, n, 64, 32 + q * 8);
            biasv[g]  = bih1[n] + bhh1[n];
        }
    }

    // zero-init both h-state buffers (h0(-1) = h1(-1) = 0)
    for (int i = tid; i < 2 * 16 * 72; i += 512) {
        ((_Float16*)h0s)[i] = (_Float16)0.0f;
        ((_Float16*)h1s)[i] = (_Float16)0.0f;
    }

    float cr[4] = {0.f, 0.f, 0.f, 0.f};   // c state for this wave's layer

    // x staging (layer-0 waves only): thread -> (row xm, 2 consecutive floats)
    const int xm = (tid >> 4) & 15;
    const int xf = (tid & 15) * 2;
    const float* xrow = x + ((size_t)(b0 + xm) * TT) * II + xf;
    float2 xbuf = {0.f, 0.f};
    if (isL0) {
        float2 x0 = *(const float2*)(xrow);            // x(0) -> xs[0]
        xs[0][xm][xf]     = (_Float16)x0.x;
        xs[0][xm][xf + 1] = (_Float16)x0.y;
        if (TT > 1) xbuf = *(const float2*)(xrow + 1 * II);  // x(1) in regs
    }

    // Iteration k: waves 0-3 compute h0(k) (k < TT); waves 4-7 compute h1(k-1)
    // (k >= 1). h*(k) is written to buf[k&1]; iter k reads h*(k-1) from
    // buf[(k+1)&1]. x(k) lives in xs[k&1], staged during iter k-1.
    // Single barrier per iter: read-buffer and write-buffer never alias, and
    // writes to a buffer are separated from its readers by the barrier.
    for (int k = 0; k <= TT; ++k) {
        __syncthreads();

        const int rd = (k + 1) & 1;
        const int wr = k & 1;
        const bool doL0 = isL0 && (k < TT);
        const bool doL1 = (!isL0) && (k >= 1);
        float hnew[4];
        float2 xnew = xbuf;

        if (doL0) {
            // gates = bias0 + x(k) Wih0^T + h0(k-1) Whh0^T
            half8 xfrag = *(const half8*)&xs[wr][lr][q * 8];      // x(k) in xs[k&1]
            half8 h0a   = *(const half8*)&h0s[rd][lr][q * 8];
            half8 h0b   = *(const half8*)&h0s[rd][lr][32 + q * 8];
            if (k + 2 < TT) xnew = *(const float2*)(xrow + (size_t)(k + 2) * II);
            floatx4 a0[4];
            #pragma unroll
            for (int g = 0; g < 4; ++g) {
                floatx4 acc = {biasv[g], biasv[g], biasv[g], biasv[g]};
                acc = __builtin_amdgcn_mfma_f32_16x16x32_f16(xfrag, bx0[g],    acc, 0, 0, 0);
                acc = __builtin_amdgcn_mfma_f32_16x16x32_f16(h0a,   bh0[g][0], acc, 0, 0, 0);
                acc = __builtin_amdgcn_mfma_f32_16x16x32_f16(h0b,   bh0[g][1], acc, 0, 0, 0);
                a0[g] = acc;
            }
            #pragma unroll
            for (int r = 0; r < 4; ++r) {
                float sf = fsig(a0[1][r]);
                float c  = fmaf(sf, cr[r], sig_tanh(a0[0][r], a0[2][r]));
                cr[r] = c;
                hnew[r] = sig_tanh(a0[3][r], c);
            }
        }
        if (doL1) {
            // gates = bias1 + h0(k-1) Wih1^T + h1(k-2) Whh1^T
            half8 g0a = *(const half8*)&h0s[rd][lr][q * 8];
            half8 g0b = *(const half8*)&h0s[rd][lr][32 + q * 8];
            half8 h1a = *(const half8*)&h1s[rd][lr][q * 8];
            half8 h1b = *(const half8*)&h1s[rd][lr][32 + q * 8];
            floatx4 a1[4];
            #pragma unroll
            for (int g = 0; g < 4; ++g) {
                floatx4 acc = {biasv[g], biasv[g], biasv[g], biasv[g]};
                acc = __builtin_amdgcn_mfma_f32_16x16x32_f16(g0a, bi1[g][0], acc, 0, 0, 0);
                acc = __builtin_amdgcn_mfma_f32_16x16x32_f16(g0b, bi1[g][1], acc, 0, 0, 0);
                acc = __builtin_amdgcn_mfma_f32_16x16x32_f16(h1a, bh1[g][0], acc, 0, 0, 0);
                acc = __builtin_amdgcn_mfma_f32_16x16x32_f16(h1b, bh1[g][1], acc, 0, 0, 0);
                a1[g] = acc;
            }
            #pragma unroll
            for (int r = 0; r < 4; ++r) {
                float sf = fsig(a1[1][r]);
                float c  = fmaf(sf, cr[r], sig_tanh(a1[0][r], a1[2][r]));
                cr[r] = c;
                hnew[r] = sig_tanh(a1[3][r], c);
            }
        }

        // writes go to buf[wr]; readers of buf[wr] are past the next barrier
        if (doL0) {
            #pragma unroll
            for (int r = 0; r < 4; ++r)
                h0s[wr][q * 4 + r][w4 * 16 + lr] = (_Float16)hnew[r];
            if (k + 1 < TT) {                       // stage x(k+1) -> xs[(k+1)&1]
                xs[rd][xm][xf]     = (_Float16)xbuf.x;
                xs[rd][xm][xf + 1] = (_Float16)xbuf.y;
            }
            xbuf = xnew;
        }
        if (doL1) {
            if (k == TT) {
                #pragma unroll
                for (int r = 0; r < 4; ++r)
                    h1f[q * 4 + r][w4 * 16 + lr] = hnew[r];
            } else {
                #pragma unroll
                for (int r = 0; r < 4; ++r)
                    h1s[wr][q * 4 + r][w4 * 16 + lr] = (_Float16)hnew[r];
            }
        }
    }
    __syncthreads();

    // ---- classifier (fp32): hidden = relu(hT Wc1^T + bc1); out = hidden Wc2^T + bc2
    if (tid < 256) {
        int m = tid >> 4;
        int u = (tid & 15) * 2;
        float a = bc1[u], b = bc1[u + 1];
        const float* w0 = Wc1 + u * 64;
        const float* w1 = Wc1 + (u + 1) * 64;
        #pragma unroll 8
        for (int kk = 0; kk < 64; ++kk) {
            float hv = h1f[m][kk];
            a += hv * w0[kk];
            b += hv * w1[kk];
        }
        hid[m][u]     = fmaxf(a, 0.f);
        hid[m][u + 1] = fmaxf(b, 0.f);
    }
    __syncthreads();
    if (tid < 16) {
        float o = bc2[0];
        #pragma unroll
        for (int u = 0; u < 32; ++u) o += hid[tid][u] * Wc2[u];
        out[b0 + tid] = o;
    }
}

extern "C" void kernel_launch(void* const* d_in, const int* in_sizes, int n_in,
                              void* d_out, int out_size, void* d_ws, size_t ws_size,
                              hipStream_t stream) {
    (void)in_sizes; (void)n_in; (void)d_ws; (void)ws_size; (void)out_size;
    const float* x    = (const float*)d_in[0];
    const float* Wih0 = (const float*)d_in[1];
    const float* Whh0 = (const float*)d_in[2];
    const float* bih0 = (const float*)d_in[3];
    const float* bhh0 = (const float*)d_in[4];
    const float* Wih1 = (const float*)d_in[5];
    const float* Whh1 = (const float*)d_in[6];
    const float* bih1 = (const float*)d_in[7];
    const float* bhh1 = (const float*)d_in[8];
    const float* Wc1  = (const float*)d_in[9];
    const float* bc1  = (const float*)d_in[10];
    const float* Wc2  = (const float*)d_in[11];
    const float* bc2  = (const float*)d_in[12];
    lstm_fused<<<dim3(256), dim3(512), 0, stream>>>(
        x, Wih0, Whh0, bih0, bhh0, Wih1, Whh1, bih1, bhh1, Wc1, bc1, Wc2, bc2,
        (float*)d_out);
}